// Round 10
// baseline (1540.367 us; speedup 1.0000x reference)
//
#include <hip/hip_runtime.h>
#include <hip/hip_fp16.h>

#define N_NODES 500000
#define N_EDGES 1000000
#define N_GRAPHS 20000

typedef _Float16 f16x8 __attribute__((ext_vector_type(8)));
typedef float f32x4 __attribute__((ext_vector_type(4)));

__global__ __launch_bounds__(256) void fill_u32(unsigned* p, unsigned v, int n) {
  int i = blockIdx.x * 256 + threadIdx.x;
  if (i < n) p[i] = v;
}

__global__ __launch_bounds__(256) void hist_dst(const int* __restrict__ dst, int* cnt, int e) {
  int i = blockIdx.x * 256 + threadIdx.x;
  if (i < e) atomicAdd(&cnt[dst[i]], 1);
}

// zero npad u32 words per row at [r*stride + off .. +npad)
__global__ __launch_bounds__(256) void pad_zero_u32(unsigned* p, int stride, int off, int npad, int rows) {
  int i = blockIdx.x * 256 + threadIdx.x;
  if (i >= rows * npad) return;
  int r = i / npad, j = i - r * npad;
  p[(size_t)r * stride + off + j] = 0u;
}

// ---- 2-level exclusive scan over deg[N] (1024 elems/block) ----
__global__ __launch_bounds__(256) void scanA(const int* __restrict__ deg, int* __restrict__ loc,
                                             int* __restrict__ partials, int n) {
  __shared__ int ts[256];
  int b = blockIdx.x, t = threadIdx.x;
  int base = b * 1024 + t * 4;
  int v[4], s = 0;
#pragma unroll
  for (int j = 0; j < 4; ++j) {
    v[j] = (base + j < n) ? deg[base + j] : 0;
    s += v[j];
  }
  ts[t] = s;
  __syncthreads();
  for (int off = 1; off < 256; off <<= 1) {
    int x = (t >= off) ? ts[t - off] : 0;
    __syncthreads();
    ts[t] += x;
    __syncthreads();
  }
  if (t == 255) partials[b] = ts[255];
  int run = ts[t] - s;  // exclusive
#pragma unroll
  for (int j = 0; j < 4; ++j) {
    if (base + j < n) loc[base + j] = run;
    run += v[j];
  }
}

__global__ __launch_bounds__(512) void scanB(int* partials, int nb) {
  __shared__ int s[512];
  int t = threadIdx.x;
  s[t] = (t < nb) ? partials[t] : 0;
  __syncthreads();
  if (t == 0) {
    int run = 0;
    for (int i = 0; i < nb; ++i) { int v = s[i]; s[i] = run; run += v; }
  }
  __syncthreads();
  if (t < nb) partials[t] = s[t];
}

__global__ __launch_bounds__(256) void scanC(int* __restrict__ rowptr, const int* __restrict__ partials,
                                             int* __restrict__ cur, int n, int e) {
  int i = blockIdx.x * 256 + threadIdx.x;
  if (i < n) {
    int v = rowptr[i] + partials[i >> 10];
    rowptr[i] = v;
    cur[i] = v;
  }
  if (i == 0) rowptr[n] = e;
}

__global__ __launch_bounds__(256) void dinv_k(const int* __restrict__ rowptr, float* dinv, int n) {
  int i = blockIdx.x * 256 + threadIdx.x;
  if (i < n) dinv[i] = rsqrtf(1.0f + (float)(rowptr[i + 1] - rowptr[i]));
}

__global__ __launch_bounds__(256) void bucket(const int* __restrict__ src, const int* __restrict__ dst,
                                              int* __restrict__ cur, int* __restrict__ ssrc, int e) {
  int i = blockIdx.x * 256 + threadIdx.x;
  if (i < e) ssrc[atomicAdd(&cur[dst[i]], 1)] = src[i];
}

// ell[n] = {deg, s0, s1, s2} (first 3 srcs inline; overflow stays in CSR)
__global__ __launch_bounds__(256) void ell_build(const int* __restrict__ rowptr,
                                                 const int* __restrict__ ssrc,
                                                 int4* __restrict__ ell, int n) {
  int i = blockIdx.x * 256 + threadIdx.x;
  if (i >= n) return;
  int r0 = rowptr[i], r1 = rowptr[i + 1];
  int deg = r1 - r0;
  int4 e;
  e.x = deg;
  e.y = (deg > 0) ? ssrc[r0] : 0;
  e.z = (deg > 1) ? ssrc[r0 + 1] : 0;
  e.w = (deg > 2) ? ssrc[r0 + 2] : 0;
  ell[i] = e;
}

// gstart[g] = first node index of graph g (batch sorted); gstart[G] = N
__global__ __launch_bounds__(256) void graph_starts(const int* __restrict__ batch,
                                                    int* __restrict__ gstart, int n) {
  int i = blockIdx.x * 256 + threadIdx.x;
  if (i < n) {
    int b = batch[i];
    int bp = (i == 0) ? -1 : batch[i - 1];
    for (int g = bp + 1; g <= b; ++g) gstart[g] = i;
  } else if (i == n) {
    int bl = batch[n - 1];
    for (int g = bl + 1; g <= N_GRAPHS; ++g) gstart[g] = n;
  }
}

// WT[c][k'] = f16(W[k][c]); CHUNK96: k'=(96-blk) layout, valid (k'%96)<78, k=78*(k'/96)+k'%96
template <int CHUNK96>
__global__ __launch_bounds__(256) void wt_conv(const float* __restrict__ W, _Float16* __restrict__ WT,
                                               int K, int Nout, int ldw, int KP, int total) {
  int i = blockIdx.x * 256 + threadIdx.x;
  if (i >= total) return;
  int c = i / KP, kp = i - c * KP;
  int k; bool valid;
  if (CHUNK96) { int blk = kp / 96, r = kp - blk * 96; k = blk * 78 + r; valid = (r < 78) && (k < K); }
  else { k = kp; valid = kp < K; }
  WT[i] = (valid && c < Nout) ? (_Float16)W[(size_t)k * ldw + c] : (_Float16)0.f;
}

// Xh[n, 0:96] = f16(x[n, 0:78]), zero pad
__global__ __launch_bounds__(256) void xconv(const float* __restrict__ x, _Float16* __restrict__ Xh) {
  unsigned idx = blockIdx.x * 256u + threadIdx.x;
  if (idx >= (unsigned)N_NODES * 48u) return;
  unsigned n = idx / 48u, c2 = idx - n * 48u;
  __half2 h = __floats2half2_rn(0.f, 0.f);
  if (c2 < 39u) {
    float2 v = *reinterpret_cast<const float2*>(x + (size_t)n * 78 + 2 * c2);
    h = __floats2half2_rn(v.x, v.y);
  }
  *reinterpret_cast<__half2*>((__half*)Xh + (size_t)n * 96 + 2 * c2) = h;
}

// Direct-register MFMA GEMM. in [M,KP] f16 zero-padded; WT [*,KP] f16 pre-transposed
// (rows padded to multiple of 80, zeros). Tile 128x80, 4 waves.
// BLDS=1: stage B once in LDS in fragment-linear order (lane i at byte 16*i ->
// sequential ds_read_b128, conflict-free), single barrier, no in-loop barriers.
// OUT_MODE 0: v*rs[row] -> f16 ; 1: relu(v+bo) -> f16 ; 2: v+bo -> f32
template <int KP, int OUT_MODE, int BLDS>
__global__ __launch_bounds__(256) void gemm_direct(
    const _Float16* __restrict__ in, const _Float16* __restrict__ WT,
    void* __restrict__ outp, const float* __restrict__ rs, const float* __restrict__ bo,
    int M, int Nout, int LDO) {
  constexpr int NS = KP / 32;
  __shared__ _Float16 Bs[BLDS ? 5 * NS * 64 * 8 : 8];
  const int tid = threadIdx.x;
  const int lane = tid & 63;
  const int wid = tid >> 6;
  const int row0 = blockIdx.y * 128;
  const int col0 = blockIdx.x * 80;
  const int koff = (lane >> 4) * 8;
  const int gr0 = row0 + wid * 32 + (lane & 15);
  const bool v0 = gr0 < M, v1 = (gr0 + 16) < M;
  const _Float16* a0 = in + (size_t)gr0 * KP + koff;
  const _Float16* a1 = a0 + (size_t)16 * KP;
  const _Float16* bp = WT + (size_t)(col0 + (lane & 15)) * KP + koff;

  if (BLDS) {
    // stage all 5*NS*64 B-fragments: frag i -> lane i&63, nf (i>>6)%5, step i/320
    for (int i = tid; i < 5 * NS * 64; i += 256) {
      int l = i & 63;
      int nf = (i >> 6) % 5;
      int s = i / 320;
      int col = col0 + nf * 16 + (l & 15);
      int k = s * 32 + ((l >> 4) << 3);
      *reinterpret_cast<uint4*>(&Bs[(size_t)i * 8]) =
          *reinterpret_cast<const uint4*>(WT + (size_t)col * KP + k);
    }
    __syncthreads();
  }

  const f16x8 zf = {0, 0, 0, 0, 0, 0, 0, 0};
  const f32x4 z4 = {0.f, 0.f, 0.f, 0.f};
  f32x4 acc[2][5];
#pragma unroll
  for (int a = 0; a < 2; ++a)
#pragma unroll
    for (int b = 0; b < 5; ++b) acc[a][b] = z4;

#pragma unroll
  for (int s = 0; s < NS; ++s) {
    f16x8 af0 = v0 ? *reinterpret_cast<const f16x8*>(a0 + s * 32) : zf;
    f16x8 af1 = v1 ? *reinterpret_cast<const f16x8*>(a1 + s * 32) : zf;
    f16x8 bf[5];
#pragma unroll
    for (int nf = 0; nf < 5; ++nf) {
      if (BLDS)
        bf[nf] = *reinterpret_cast<const f16x8*>(&Bs[((size_t)(s * 5 + nf) * 64 + lane) * 8]);
      else
        bf[nf] = *reinterpret_cast<const f16x8*>(bp + (size_t)nf * 16 * KP + s * 32);
    }
#pragma unroll
    for (int nf = 0; nf < 5; ++nf) {
      acc[0][nf] = __builtin_amdgcn_mfma_f32_16x16x32_f16(af0, bf[nf], acc[0][nf], 0, 0, 0);
      acc[1][nf] = __builtin_amdgcn_mfma_f32_16x16x32_f16(af1, bf[nf], acc[1][nf], 0, 0, 0);
    }
  }

  // epilogue: C/D col=lane&15, row=(lane>>4)*4+reg
#pragma unroll
  for (int rf = 0; rf < 2; ++rf) {
#pragma unroll
    for (int j = 0; j < 4; ++j) {
      int gr = row0 + wid * 32 + rf * 16 + (lane >> 4) * 4 + j;
      if (gr >= M) continue;
      float sc = (OUT_MODE == 0) ? rs[gr] : 0.f;
#pragma unroll
      for (int nf = 0; nf < 5; ++nf) {
        int oc = col0 + nf * 16 + (lane & 15);
        if (oc >= Nout) continue;
        float v = acc[rf][nf][j];
        if (OUT_MODE == 0) {
          ((_Float16*)outp)[(size_t)gr * LDO + oc] = (_Float16)(v * sc);
        } else if (OUT_MODE == 1) {
          ((_Float16*)outp)[(size_t)gr * LDO + oc] = (_Float16)fmaxf(v + bo[oc], 0.f);
        } else {
          ((float*)outp)[(size_t)gr * LDO + oc] = v + bo[oc];
        }
      }
    }
  }
}

__device__ inline void acc8(float* a, uint4 v) {
  const __half2* h = reinterpret_cast<const __half2*>(&v);
#pragma unroll
  for (int j = 0; j < 4; ++j) {
    float2 f = __half22float2(h[j]);
    a[2 * j] += f.x;
    a[2 * j + 1] += f.y;
  }
}

// Fused segment-sum + transform, 16B per thread (10 threads/node, hs stride 80).
// ELL fast path: one int4 (L1-broadcast across the node's 10 lanes) gives deg +
// first 3 srcs -> self + up to 3 INDEPENDENT gathers; CSR loop only when deg>3.
// dsth[n, wcoff + q*8 + j] = f16(relu(dinv[n]*(hs[n]+Σ hs[src]) + b[boff+q*8+j]))
__global__ __launch_bounds__(256) void aggregate16B(
    const _Float16* __restrict__ hs, const int4* __restrict__ ell,
    const int* __restrict__ rowptr, const int* __restrict__ ssrc,
    const float* __restrict__ dinv, const float* __restrict__ b,
    _Float16* __restrict__ dsth, int ldo, int boff, int wcoff) {
  unsigned idx = blockIdx.x * 256u + threadIdx.x;
  if (idx >= (unsigned)N_NODES * 10u) return;
  unsigned n = idx / 10u, q = idx - n * 10u;
  const _Float16* hbase = hs + 8u * q;
  int4 e = ell[n];
  const int deg = e.x;
  uint4 sv = *reinterpret_cast<const uint4*>(hbase + (size_t)n * 80);
  uint4 g0, g1, g2;
  if (deg > 0) g0 = *reinterpret_cast<const uint4*>(hbase + (size_t)e.y * 80);
  if (deg > 1) g1 = *reinterpret_cast<const uint4*>(hbase + (size_t)e.z * 80);
  if (deg > 2) g2 = *reinterpret_cast<const uint4*>(hbase + (size_t)e.w * 80);
  float a[8];
  {
    const __half2* h = reinterpret_cast<const __half2*>(&sv);
#pragma unroll
    for (int j = 0; j < 4; ++j) {
      float2 f = __half22float2(h[j]);
      a[2 * j] = f.x;
      a[2 * j + 1] = f.y;
    }
  }
  if (deg > 0) acc8(a, g0);
  if (deg > 1) acc8(a, g1);
  if (deg > 2) acc8(a, g2);
  if (deg > 3) {
    int r = rowptr[n] + 3, r1 = r + deg - 3;
    for (; r + 2 <= r1; r += 2) {
      uint4 va = *reinterpret_cast<const uint4*>(hbase + (size_t)ssrc[r] * 80);
      uint4 vb = *reinterpret_cast<const uint4*>(hbase + (size_t)ssrc[r + 1] * 80);
      acc8(a, va);
      acc8(a, vb);
    }
    if (r < r1) {
      uint4 va = *reinterpret_cast<const uint4*>(hbase + (size_t)ssrc[r] * 80);
      acc8(a, va);
    }
  }
  float di = dinv[n];
  _Float16 ov[8];
#pragma unroll
  for (int j = 0; j < 8; ++j) {
    int col = q * 8 + j;
    float bv = (col < 78) ? b[boff + col] : 0.f;
    ov[j] = (_Float16)fmaxf(fmaf(di, a[j], bv), 0.f);
  }
  *reinterpret_cast<uint4*>(dsth + (size_t)n * ldo + wcoff + q * 8) =
      *reinterpret_cast<const uint4*>(ov);
}

// Mean-pool over contiguous node range: GA[g, coff96 + 2p..] = (1/cnt) Σ_n TR[n, 2p..]
__global__ __launch_bounds__(256) void pool_seq(
    const _Float16* __restrict__ TR, const int* __restrict__ gstart,
    _Float16* __restrict__ GA, int coff96) {
  unsigned idx = blockIdx.x * 256u + threadIdx.x;
  if (idx >= (unsigned)N_GRAPHS * 39u) return;
  unsigned g = idx / 39u, p = idx - g * 39u;
  int n0 = gstart[g], n1 = gstart[g + 1];
  const __half* base = (const __half*)TR + 2 * p;
  float ax = 0.f, ay = 0.f, bx = 0.f, by = 0.f;
  int n = n0;
  for (; n + 2 <= n1; n += 2) {
    __half2 va = *reinterpret_cast<const __half2*>(base + (size_t)n * 80);
    __half2 vb = *reinterpret_cast<const __half2*>(base + (size_t)(n + 1) * 80);
    ax += __half2float(va.x); ay += __half2float(va.y);
    bx += __half2float(vb.x); by += __half2float(vb.y);
  }
  if (n < n1) {
    __half2 va = *reinterpret_cast<const __half2*>(base + (size_t)n * 80);
    ax += __half2float(va.x); ay += __half2float(va.y);
  }
  float gi = 1.0f / fmaxf((float)(n1 - n0), 1.0f);
  *reinterpret_cast<__half2*>(GA + (size_t)g * 384 + coff96 + 2 * p) =
      __floats2half2_rn((ax + bx) * gi, (ay + by) * gi);
}

extern "C" void kernel_launch(void* const* d_in, const int* in_sizes, int n_in,
                              void* d_out, int out_size, void* d_ws, size_t ws_size,
                              hipStream_t stream) {
  const float* x   = (const float*)d_in[0];
  const int* ei    = (const int*)d_in[1];
  const int* batch = (const int*)d_in[2];
  const float* W1 = (const float*)d_in[3];
  const float* b1 = (const float*)d_in[4];
  const float* W2 = (const float*)d_in[5];
  const float* b2 = (const float*)d_in[6];
  const float* W3 = (const float*)d_in[7];
  const float* b3 = (const float*)d_in[8];
  const float* fW1 = (const float*)d_in[9];
  const float* fb1 = (const float*)d_in[10];
  const float* fW2 = (const float*)d_in[11];
  const float* fb2 = (const float*)d_in[12];
  float* out = (float*)d_out;

  const int Nn = N_NODES, E = N_EDGES, G = N_GRAPHS;
  const int* src = ei;
  const int* dst = ei + E;

  // ---- workspace layout (~404 MB) ----
  _Float16* AGG2h = (_Float16*)d_ws;                      // [N,192]
  _Float16* Xh    = AGG2h;                                // [N,96]  (dead after L1 gemm)
  _Float16* AGG1h = AGG2h + (size_t)Nn * 192;             // [N,96]
  _Float16* TR    = AGG1h;                                // [N,80]  (after L2 gemms done)
  _Float16* HSh   = AGG1h + (size_t)Nn * 96;              // [N,80]
  _Float16* fc1   = HSh;                                  // [G,1056] (after last L3 agg)
  _Float16* GA    = HSh + (size_t)Nn * 80;                // [G,384] chunk-strided
  _Float16* W1T   = GA + (size_t)G * 384;                 // [80][96]
  _Float16* W2T   = W1T + 80 * 96;                        // [160][96]
  _Float16* W3T   = W2T + 160 * 96;                       // [320][192] chunk96
  _Float16* fW1T  = W3T + 320 * 192;                      // [1040][384] chunk96
  _Float16* fW2T  = fW1T + (size_t)1040 * 384;            // [160][1056]
  float* dinv     = (float*)(fW2T + (size_t)160 * 1056);  // [N]
  int* rowptr     = (int*)(dinv + Nn);                    // [N+1]
  int* cur        = rowptr + Nn + 1;                      // [N]
  int* ssrc       = cur + Nn;                             // [E]
  int* partials   = ssrc + E;                             // [512]
  int* gstart     = partials + 512;                       // [G+1]
  int4* ell = (int4*)(((uintptr_t)(gstart + G + 1) + 15) & ~(uintptr_t)15);  // [N]

  dim3 blk(256);
  const int gN10 = (int)(((unsigned)Nn * 10u + 255u) / 256u);
  const int gG39 = (int)(((unsigned)G * 39u + 255u) / 256u);
  const dim3 nodeGrid(1, (Nn + 127) / 128);
  const int NB = (Nn + 1023) / 1024;  // 489

  // ---- CSR build (dst-sorted src list) + ELL ----
  fill_u32<<<(Nn + 255) / 256, blk, 0, stream>>>((unsigned*)cur, 0u, Nn);
  hist_dst<<<(E + 255) / 256, blk, 0, stream>>>(dst, cur, E);
  scanA<<<NB, blk, 0, stream>>>(cur, rowptr, partials, Nn);
  scanB<<<1, 512, 0, stream>>>(partials, NB);
  scanC<<<(Nn + 255) / 256, blk, 0, stream>>>(rowptr, partials, cur, Nn, E);
  dinv_k<<<(Nn + 255) / 256, blk, 0, stream>>>(rowptr, dinv, Nn);
  bucket<<<(E + 255) / 256, blk, 0, stream>>>(src, dst, cur, ssrc, E);
  ell_build<<<(Nn + 255) / 256, blk, 0, stream>>>(rowptr, ssrc, ell, Nn);
  graph_starts<<<(Nn + 256) / 256, blk, 0, stream>>>(batch, gstart, Nn);

  // ---- fp16 transposed weights ----
  wt_conv<0><<<(80 * 96 + 255) / 256, blk, 0, stream>>>(W1, W1T, 78, 78, 78, 96, 80 * 96);
  wt_conv<0><<<(160 * 96 + 255) / 256, blk, 0, stream>>>(W2, W2T, 78, 156, 156, 96, 160 * 96);
  wt_conv<1><<<(320 * 192 + 255) / 256, blk, 0, stream>>>(W3, W3T, 156, 312, 312, 192, 320 * 192);
  wt_conv<1><<<(1040 * 384 + 255) / 256, blk, 0, stream>>>(fW1, fW1T, 312, 1024, 1024, 384, 1040 * 384);
  wt_conv<0><<<(160 * 1056 + 255) / 256, blk, 0, stream>>>(fW2, fW2T, 1024, 128, 128, 1056, 160 * 1056);

  // ---- pads (ws poisoned 0xAA once) ----
  pad_zero_u32<<<(Nn + 255) / 256, blk, 0, stream>>>((unsigned*)HSh, 40, 39, 1, Nn);
  pad_zero_u32<<<((Nn * 8) + 255) / 256, blk, 0, stream>>>((unsigned*)AGG1h, 48, 40, 8, Nn);
  pad_zero_u32<<<((Nn * 8) + 255) / 256, blk, 0, stream>>>((unsigned*)AGG2h, 96, 40, 8, Nn);
  pad_zero_u32<<<((Nn * 8) + 255) / 256, blk, 0, stream>>>((unsigned*)AGG2h, 96, 88, 8, Nn);
  for (int c = 0; c < 4; ++c)
    pad_zero_u32<<<((G * 9) + 255) / 256, blk, 0, stream>>>((unsigned*)GA, 192, 48 * c + 39, 9, G);

  // ---- x -> f16 [N,96] ----
  xconv<<<(int)(((unsigned)Nn * 48u + 255u) / 256u), blk, 0, stream>>>(x, Xh);

  // ---- layer 1 ----
  gemm_direct<96, 0, 1><<<nodeGrid, blk, 0, stream>>>(Xh, W1T, HSh, dinv, nullptr, Nn, 78, 80);
  aggregate16B<<<gN10, blk, 0, stream>>>(HSh, ell, rowptr, ssrc, dinv, b1, AGG1h, 96, 0, 0);

  // ---- layer 2 (2 chunks of 78 -> AGG2h chunk-strided) ----
  for (int c = 0; c < 2; ++c) {
    gemm_direct<96, 0, 1><<<nodeGrid, blk, 0, stream>>>(
        AGG1h, W2T + (size_t)(78 * c) * 96, HSh, dinv, nullptr, Nn, 78, 80);
    aggregate16B<<<gN10, blk, 0, stream>>>(HSh, ell, rowptr, ssrc, dinv, b2, AGG2h, 192, 78 * c, 96 * c);
  }

  // ---- layer 3 (4 chunks): gemm -> relu-transform (TR) -> seq pool ----
  for (int c = 0; c < 4; ++c) {
    gemm_direct<192, 0, 1><<<nodeGrid, blk, 0, stream>>>(
        AGG2h, W3T + (size_t)(78 * c) * 192, HSh, dinv, nullptr, Nn, 78, 80);
    aggregate16B<<<gN10, blk, 0, stream>>>(HSh, ell, rowptr, ssrc, dinv, b3, TR, 80, 78 * c, 0);
    pool_seq<<<gG39, blk, 0, stream>>>(TR, gstart, GA, 96 * c);
  }

  // ---- fc1 pad cols (1024..1055); HSh dead after last aggregate ----
  pad_zero_u32<<<((G * 16) + 255) / 256, blk, 0, stream>>>((unsigned*)fc1, 528, 512, 16, G);

  // ---- FC1: relu(GA @ fW1 + fb1) -> fc1 f16 (B staged in 60 KB LDS) ----
  {
    dim3 g((1024 + 79) / 80, (G + 127) / 128);  // 13 x 157
    gemm_direct<384, 1, 1><<<g, blk, 0, stream>>>(GA, fW1T, fc1, nullptr, fb1, G, 1024, 1056);
  }
  // ---- FC2: out = fc1 @ fW2 + fb2 (f32) ----
  {
    dim3 g((128 + 79) / 80, (G + 127) / 128);  // 2 x 157
    gemm_direct<1056, 2, 0><<<g, blk, 0, stream>>>(fc1, fW2T, out, nullptr, fb2, G, 128, 128);
  }
}